// Round 5
// baseline (215.648 us; speedup 1.0000x reference)
//
#include <hip/hip_runtime.h>
#include <hip/hip_fp16.h>
#include <math.h>

// B=65536 rows, DIM=256, OUT=10.
// z = x@w_in + b_in; 4x { z = (z + tanh(z) + b_i) @ inv(W_i) }; out = softmax(z@w_out + b_out).
// Newton on a linear system converges in one step => z = c @ W^{-1}.
// Round 19: fused3_k with SOFTWARE-PIPELINED zf + setprio; ns_poly 2-row slabs.
//   R18 post-mortem: sched_barrier(0) after EVERY kc step serialized
//   ds_read->wait(120cy)->MFMA(78cy) with only 2 waves/SIMD -> MfmaUtil 17%.
//   Fix: named zfA/zfB double-buffer, ZREAD(next) issued BEFORE ZMMA(cur) in each
//   fenced region (loads stay in flight across step boundaries, T3-style);
//   s_setprio(1) around MFMA clusters (T5: waves drift into EPI vs MFMA roles).
//   ns_poly: 2-row slabs, 512 poly blocks (2 waves/SIMD TLP, was 1).

typedef __attribute__((ext_vector_type(8))) short short8;
typedef __attribute__((ext_vector_type(4))) float f32x4;

// ---- helpers ----
__device__ __forceinline__ float tanh_fast(float x) {
#if __has_builtin(__builtin_amdgcn_exp2f)
  float e = __builtin_amdgcn_exp2f(x * 2.8853900817779268f);
#else
  float e = __expf(2.0f * x);
#endif
  return 1.0f - 2.0f * __builtin_amdgcn_rcpf(e + 1.0f);
}
// RNE pair pack (cold path: weights)
__device__ __forceinline__ unsigned rn_pair16(float v0, float v1) {
  __half2 h = __floats2half2_rn(v0, v1);
  return *reinterpret_cast<unsigned*>(&h);
}
// RTZ pair pack, single v_cvt_pkrtz (hot path: z)
__device__ __forceinline__ unsigned rtz_pair16(float v0, float v1) {
#if __has_builtin(__builtin_amdgcn_cvt_pkrtz)
  typedef __fp16 h2v __attribute__((ext_vector_type(2)));
  h2v h = __builtin_amdgcn_cvt_pkrtz(v0, v1);
  return *reinterpret_cast<unsigned*>(&h);
#else
  return rn_pair16(v0, v1);
#endif
}

// ---------------- Phase 1: ns_poly_k, 640 blocks ----------------
// Blocks 0..511: matrix m = bid>>7, 2-row slab r0 = (bid&127)*2:
//   P = 6I -15W +20W^2 -15W^3 +6W^4 -W^5 via 4 Horner steps (mult by original W);
//   pack fp16-RNE into pk layer m+1. (2-row slabs: 2 blocks/CU -> 2 waves/SIMD TLP.)
// Blocks 512..639: pack w_in + w_out (at 5*32768, cols>=10 zero).
// pk layout (dwords): layer*32768 + kc*4096 + cg*256 + lane*4 + d;
// word d of lane(quad,n16) = M[kb][n] lo16 | M[kb+1][n] hi16, kb=kc*32+quad*8+2d, n=cg*16+n16.
__global__ __launch_bounds__(256) void ns_poly_k(
    const float* __restrict__ w1, const float* __restrict__ w2,
    const float* __restrict__ w3, const float* __restrict__ w4,
    const float* __restrict__ w_in, const float* __restrict__ w_out,
    unsigned* __restrict__ pk) {
  const int bid = blockIdx.x;
  const int t = threadIdx.x;
  if (bid >= 512) {
    int idx = (bid - 512) * 256 + t;  // 0..32767
    {
      int kc = idx >> 12;
      int nt = (idx >> 8) & 15;
      int lane = (idx >> 2) & 63;
      int d = idx & 3;
      int n = nt * 16 + (lane & 15);
      int kb = kc * 32 + (lane >> 4) * 8 + d * 2;
      pk[idx] = rn_pair16(w_in[kb * 256 + n], w_in[(kb + 1) * 256 + n]);
    }
    int idx2 = idx + 32768;
    if (idx2 < 34816) {
      int r2 = idx2 - 32768;  // 0..2047
      int kc = r2 >> 8;
      int lane = (r2 >> 2) & 63;
      int d = r2 & 3;
      int n = lane & 15;
      int kb = kc * 32 + (lane >> 4) * 8 + d * 2;
      float v0 = (n < 10) ? w_out[kb * 10 + n] : 0.0f;
      float v1 = (n < 10) ? w_out[(kb + 1) * 10 + n] : 0.0f;
      pk[5 * 32768 + r2] = rn_pair16(v0, v1);
    }
    return;
  }
  const int m = bid >> 7;            // matrix 0..3
  const int r0 = (bid & 127) * 2;    // slab start row (2 rows)
  const float* __restrict__ W = (m == 0) ? w1 : (m == 1) ? w2 : (m == 2) ? w3 : w4;
  __shared__ float S[2][256];

  // init: P = 6I - W (slab rows r0, r0+1)
  S[0][t] = ((r0 == t) ? 6.0f : 0.0f) - W[r0 * 256 + t];
  S[1][t] = (((r0 + 1) == t) ? 6.0f : 0.0f) - W[(r0 + 1) * 256 + t];
  __syncthreads();

  const float coef[4] = {-15.0f, 20.0f, -15.0f, 6.0f};
#pragma unroll
  for (int step = 0; step < 4; ++step) {
    float acc0 = 0.0f, acc1 = 0.0f;
    for (int k = 0; k < 256; k += 4) {
      float4 sv0 = *(const float4*)&S[0][k];
      float4 sv1 = *(const float4*)&S[1][k];
      float wv0 = W[(k + 0) * 256 + t];
      float wv1 = W[(k + 1) * 256 + t];
      float wv2 = W[(k + 2) * 256 + t];
      float wv3 = W[(k + 3) * 256 + t];
      acc0 = fmaf(sv0.x, wv0, acc0); acc1 = fmaf(sv1.x, wv0, acc1);
      acc0 = fmaf(sv0.y, wv1, acc0); acc1 = fmaf(sv1.y, wv1, acc1);
      acc0 = fmaf(sv0.z, wv2, acc0); acc1 = fmaf(sv1.z, wv2, acc1);
      acc0 = fmaf(sv0.w, wv3, acc0); acc1 = fmaf(sv1.w, wv3, acc1);
    }
    __syncthreads();
    float cdiag = coef[step];
    S[0][t] = acc0 + ((r0 == t) ? cdiag : 0.0f);
    S[1][t] = acc1 + (((r0 + 1) == t) ? cdiag : 0.0f);
    __syncthreads();
  }

  // ---- pack slab (2 rows = exactly one dword per column) ----
  const int kc = r0 >> 5;
  const int quad = (r0 >> 3) & 3;
  const int d = (r0 & 7) >> 1;
  {
    int n = t;                  // column 0..255
    int nt = n >> 4;
    int n16 = n & 15;
    int lane = quad * 16 + n16;
    pk[(m + 1) * 32768 + kc * 4096 + nt * 256 + lane * 4 + d] =
        rn_pair16(S[0][n], S[1][n]);
  }
}

// ---------------- Phase 2: fused3_k (software-pipelined) ----------------
// Read the 4 z-fragments for step KC into DST (literal KC -> registers).
#define ZREAD(DST, PL, KC)                                                     \
  {                                                                            \
    _Pragma("unroll") for (int mt = 0; mt < 4; ++mt) {                         \
      int mm = mt * 16 + n16;                                                  \
      DST[mt] = *(const short8*)&(PL)[mm * 256 + ((((KC) * 4 + quad) ^ (mm & 31)) * 8)]; \
    }                                                                          \
  }
// 16 MFMAs for step KC from SRC (setprio(1) cluster, T5).
#define ZMMA(SRC, KC)                                                          \
  {                                                                            \
    __builtin_amdgcn_s_setprio(1);                                             \
    _Pragma("unroll") for (int mt = 0; mt < 4; ++mt)                           \
      _Pragma("unroll") for (int nt = 0; nt < 4; ++nt)                         \
        acc[mt][nt] = __builtin_amdgcn_mfma_f32_16x16x32_f16(                  \
            wreg[nt][KC], SRC[mt], acc[mt][nt], 0, 0, 0);                      \
    __builtin_amdgcn_s_setprio(0);                                             \
  }
// MFMA phase over plane PL: zfA/zfB double-buffer; ZREAD(next) issues BEFORE
// ZMMA(cur) inside each fenced region -> LDS latency hides under MFMA.
#define M_PHASE(PL)                                                            \
  {                                                                            \
    _Pragma("unroll") for (int mt = 0; mt < 4; ++mt)                           \
      _Pragma("unroll") for (int nt = 0; nt < 4; ++nt)                         \
        acc[mt][nt] = (f32x4){0.f, 0.f, 0.f, 0.f};                             \
    short8 zfA[4], zfB[4];                                                     \
    ZREAD(zfA, PL, 0);                                                         \
    __builtin_amdgcn_sched_barrier(0);                                         \
    ZREAD(zfB, PL, 1); ZMMA(zfA, 0); __builtin_amdgcn_sched_barrier(0);        \
    ZREAD(zfA, PL, 2); ZMMA(zfB, 1); __builtin_amdgcn_sched_barrier(0);        \
    ZREAD(zfB, PL, 3); ZMMA(zfA, 2); __builtin_amdgcn_sched_barrier(0);        \
    ZREAD(zfA, PL, 4); ZMMA(zfB, 3); __builtin_amdgcn_sched_barrier(0);        \
    ZREAD(zfB, PL, 5); ZMMA(zfA, 4); __builtin_amdgcn_sched_barrier(0);        \
    ZREAD(zfA, PL, 6); ZMMA(zfB, 5); __builtin_amdgcn_sched_barrier(0);        \
    ZREAD(zfB, PL, 7); ZMMA(zfA, 6); __builtin_amdgcn_sched_barrier(0);        \
    ZMMA(zfB, 7);                                                              \
  }

// Epilogue into plane PL: bias/tanh, cvt_pkrtz pack.
#define E_PHASE(PL, BN, BI, DOTANH)                                            \
  {                                                                            \
    _Pragma("unroll") for (int nt = 0; nt < 4; ++nt) {                         \
      int colb = wv * 64 + nt * 16 + quad * 4;                                 \
      float4 bi4 = make_float4(0.f, 0.f, 0.f, 0.f);                            \
      float4 bn4 = make_float4(0.f, 0.f, 0.f, 0.f);                            \
      if ((BI) != nullptr) bi4 = *(const float4*)((BI) + colb);                \
      if (DOTANH) bn4 = *(const float4*)((BN) + colb);                         \
      _Pragma("unroll") for (int mt = 0; mt < 4; ++mt) {                       \
        int row = mt * 16 + n16;                                               \
        float v0 = acc[mt][nt][0] + bi4.x;                                     \
        float v1 = acc[mt][nt][1] + bi4.y;                                     \
        float v2 = acc[mt][nt][2] + bi4.z;                                     \
        float v3 = acc[mt][nt][3] + bi4.w;                                     \
        if (DOTANH) {                                                          \
          v0 = v0 + tanh_fast(v0) + bn4.x;                                     \
          v1 = v1 + tanh_fast(v1) + bn4.y;                                     \
          v2 = v2 + tanh_fast(v2) + bn4.z;                                     \
          v3 = v3 + tanh_fast(v3) + bn4.w;                                     \
        }                                                                      \
        int idx = row * 256 + (((colb >> 3) ^ (row & 31)) * 8) + (colb & 7);   \
        uint2 zp;                                                              \
        zp.x = rtz_pair16(v0, v1);                                             \
        zp.y = rtz_pair16(v2, v3);                                             \
        *(uint2*)&(PL)[idx] = zp;                                              \
      }                                                                        \
    }                                                                          \
  }

// Load this wave's full 64-col weight slice for LAYER into wreg (128 VGPRs).
#define LOAD_WREG(LAYER)                                                       \
  {                                                                            \
    const unsigned* pkl = pk + (LAYER) * 32768 + wv * 1024 + ln * 4;           \
    _Pragma("unroll") for (int nt = 0; nt < 4; ++nt)                           \
      _Pragma("unroll") for (int kc = 0; kc < 8; ++kc)                         \
        wreg[nt][kc] = *(const short8*)(pkl + kc * 4096 + nt * 256);           \
  }

__global__ __launch_bounds__(256)
__attribute__((amdgpu_waves_per_eu(2, 2)))  // 2 waves/EU -> 256-reg unified budget
void fused3_k(
    const float* __restrict__ x, const unsigned* __restrict__ pk,
    const float* __restrict__ b_in,
    const float* __restrict__ b1, const float* __restrict__ b2,
    const float* __restrict__ b3, const float* __restrict__ b4,
    const float* __restrict__ b_out, float* __restrict__ out) {
  __shared__ unsigned short zpl[2 * 64 * 256];  // two z-planes, 64 KB
  const int t = threadIdx.x;
  const int ln = t & 63;
  const int wv = t >> 6;        // wave 0..3, owns cols [wv*64, wv*64+64)
  const int quad = ln >> 4;
  const int n16 = ln & 15;
  const int grow0 = blockIdx.x * 128;  // 128 rows/block (two 64-row tiles)

  short8 wreg[4][8];  // [nt][kc] — this wave's weight slice, 128 VGPRs
  f32x4 acc[4][4];    // [mt][nt] — 64 regs (AGPR side)

  LOAD_WREG(0);  // layer-0 weights in flight during x staging

  // ---- stage x as fp16 into both planes ----
#pragma unroll
  for (int i = 0; i < 32; ++i) {
    int e = i * 1024 + t * 4;
    int r = e >> 8, c = e & 255;     // r 0..127
    float4 v = *(const float4*)(x + (grow0 + r) * 256 + c);
    int u = r >> 6, rl = r & 63;
    int idx = u * 16384 + rl * 256 + (((c >> 3) ^ (rl & 31)) * 8) + (c & 7);
    uint2 zp;
    zp.x = rtz_pair16(v.x, v.y);
    zp.y = rtz_pair16(v.z, v.w);
    *(uint2*)&zpl[idx] = zp;
  }
  __syncthreads();

  unsigned short* pl0 = zpl;
  unsigned short* pl1 = zpl + 16384;
  const float* bnv[4] = {b1, b2, b3, b4};

  for (int layer = 0; layer < 5; ++layer) {
    const float* bn = (layer < 4) ? bnv[layer] : nullptr;
    const float* bi0 = (layer == 0) ? b_in : nullptr;
    const bool dt = (layer < 4);

    M_PHASE(pl0);                       // tile 0 MFMA (wreg + LDS only, no vmcnt)
    __syncthreads();
    E_PHASE(pl0, bn, bi0, dt);          // tile 0 epilogue ...
    M_PHASE(pl1);                       // ... overlapped with tile 1 MFMA
    __syncthreads();
    if (layer < 4) LOAD_WREG(layer + 1);  // wreg dead; L2 latency hides under E1
    E_PHASE(pl1, bn, bi0, dt);          // tile 1 epilogue
  }
  __syncthreads();

  // ---- logits: wave wv reduces k-slice [wv*64, wv*64+64), both tiles ----
  {
    f32x4 lacc[2][4];
#pragma unroll
    for (int u = 0; u < 2; ++u)
#pragma unroll
      for (int mt = 0; mt < 4; ++mt) lacc[u][mt] = (f32x4){0.f, 0.f, 0.f, 0.f};
    const unsigned* pw = pk + 5 * 32768 + ln * 4;
#pragma unroll
    for (int kk = 0; kk < 2; ++kk) {
      int kc = wv * 2 + kk;
      short8 wh = *(const short8*)(pw + kc * 256);
#pragma unroll
      for (int u = 0; u < 2; ++u) {
        const unsigned short* pl = zpl + u * 16384;
#pragma unroll
        for (int mt = 0; mt < 4; ++mt) {
          int mm = mt * 16 + n16;
          short8 zf = *(const short8*)&pl[mm * 256 + (((kc * 4 + quad) ^ (mm & 31)) * 8)];
          lacc[u][mt] = __builtin_amdgcn_mfma_f32_16x16x32_f16(wh, zf, lacc[u][mt], 0, 0, 0);
        }
      }
    }
    __syncthreads();  // all z reads done before pbuf overwrites planes
    // pbuf_u overlays plane u: [wave][64 rows][16 cols] floats = 16 KB per tile
#pragma unroll
    for (int u = 0; u < 2; ++u) {
      float* pbuf = (float*)(zpl + u * 16384);
#pragma unroll
      for (int mt = 0; mt < 4; ++mt) {
        int addr = wv * 1024 + (mt * 16 + n16) * 16 + quad * 4;
        *(f32x4*)&pbuf[addr] = lacc[u][mt];
      }
    }
    __syncthreads();
    if (t < 128) {
      int u = t >> 6;
      int rl = t & 63;
      const float* pbuf = (const float*)(zpl + u * 16384);
      float lg[10];
      float mx = -1e30f;
#pragma unroll
      for (int j = 0; j < 10; ++j) {
        float s = b_out[j];
#pragma unroll
        for (int w2 = 0; w2 < 4; ++w2) s += pbuf[w2 * 1024 + rl * 16 + j];
        lg[j] = s;
        mx = fmaxf(mx, s);
      }
      float sum = 0.f;
#pragma unroll
      for (int j = 0; j < 10; ++j) {
        lg[j] = __expf(lg[j] - mx);
        sum += lg[j];
      }
      float inv = 1.0f / sum;
      float* op = out + (grow0 + t) * 10;
#pragma unroll
      for (int j = 0; j < 10; ++j) op[j] = lg[j] * inv;
    }
  }
}

extern "C" void kernel_launch(void* const* d_in, const int* in_sizes, int n_in,
                              void* d_out, int out_size, void* d_ws, size_t ws_size,
                              hipStream_t stream) {
  const float* x     = (const float*)d_in[0];
  const float* w_in  = (const float*)d_in[1];
  const float* b_in  = (const float*)d_in[2];
  const float* w_out = (const float*)d_in[3];
  const float* b_out = (const float*)d_in[4];
  const float* w1 = (const float*)d_in[5];
  const float* b1 = (const float*)d_in[6];
  const float* w2 = (const float*)d_in[7];
  const float* b2 = (const float*)d_in[8];
  const float* w3 = (const float*)d_in[9];
  const float* b3 = (const float*)d_in[10];
  const float* w4 = (const float*)d_in[11];
  const float* b4 = (const float*)d_in[12];
  float* out = (float*)d_out;

  unsigned* pk = (unsigned*)d_ws;  // 165888 dwords

  ns_poly_k<<<640, 256, 0, stream>>>(w1, w2, w3, w4, w_in, w_out, pk);
  fused3_k<<<512, 256, 0, stream>>>(x, pk, b_in, b1, b2, b3, b4, b_out, out);
}

// Round 6
// 207.378 us; speedup vs baseline: 1.0399x; 1.0399x over previous
//
#include <hip/hip_runtime.h>
#include <hip/hip_fp16.h>
#include <math.h>

// B=65536 rows, DIM=256, OUT=10.
// z = x@w_in + b_in; 4x { z = (z + tanh(z) + b_i) @ inv(W_i) }; out = softmax(z@w_out + b_out).
// Newton on a linear system converges in one step => z = c @ W^{-1}.
// Round 20: fused3_k K-SPLIT weight residency — fits 128 arch + 128 AGPR exactly.
//   R18/R19 post-mortem: at waves_per_eu(2,2) the 512-reg/SIMD unified file splits
//   128 arch VGPR + 128 AGPR (rocprof VGPR_Count=128 both rounds). wreg[4][8]=128
//   filled the ENTIRE arch file -> 26..87 dw/thread scratch (WRITE_SIZE 16->47 MB).
//   Fix: wreg[4][4] (kc half, 64 VGPRs). Per layer: pass kc0-3 over both tiles,
//   reload wreg (regs dead) with kc4-7, pass kc4-7 into the SAME accumulators.
//   acc[2][4][4] = 128 AGPR = exactly the AGPR file. No extra LDS reads, no extra
//   weight traffic. No per-step sched_barriers (compiler's pressure-aware scheduler
//   pipelines ds_reads); coarse sched_barrier(0) per pass; setprio(1) per MFMA pass.
//   ns_poly: reverted to 4-row/384-block (R19's 2-row doubled W traffic, -10us).
//   z planes: 2 x 64x256 fp16, XOR swizzle idx16(r,k) = r*256 + ((k>>3)^(r&31))*8 + (k&7).

typedef __attribute__((ext_vector_type(8))) short short8;
typedef __attribute__((ext_vector_type(4))) float f32x4;

// ---- helpers ----
__device__ __forceinline__ float tanh_fast(float x) {
#if __has_builtin(__builtin_amdgcn_exp2f)
  float e = __builtin_amdgcn_exp2f(x * 2.8853900817779268f);
#else
  float e = __expf(2.0f * x);
#endif
  return 1.0f - 2.0f * __builtin_amdgcn_rcpf(e + 1.0f);
}
// RNE pair pack (cold path: weights)
__device__ __forceinline__ unsigned rn_pair16(float v0, float v1) {
  __half2 h = __floats2half2_rn(v0, v1);
  return *reinterpret_cast<unsigned*>(&h);
}
// RTZ pair pack, single v_cvt_pkrtz (hot path: z)
__device__ __forceinline__ unsigned rtz_pair16(float v0, float v1) {
#if __has_builtin(__builtin_amdgcn_cvt_pkrtz)
  typedef __fp16 h2v __attribute__((ext_vector_type(2)));
  h2v h = __builtin_amdgcn_cvt_pkrtz(v0, v1);
  return *reinterpret_cast<unsigned*>(&h);
#else
  return rn_pair16(v0, v1);
#endif
}

// ---------------- Phase 1: one kernel, 384 blocks (R4 version, proven) ----------------
// Blocks 0..255: matrix m = bid>>6, 4-row slab r0 = (bid&63)*4:
//   P = 6I -15W +20W^2 -15W^3 +6W^4 -W^5 via 4 Horner steps (mult by original W);
//   pack fp16-RNE into pk layer m+1.
// Blocks 256..383: pack w_in + w_out (at 5*32768, cols>=10 zero).
// pk layout (dwords): layer*32768 + kc*4096 + cg*256 + lane*4 + d;
// word d of lane(quad,n16) = M[kb][n] lo16 | M[kb+1][n] hi16, kb=kc*32+quad*8+2d, n=cg*16+n16.
__global__ __launch_bounds__(256) void ns_poly_k(
    const float* __restrict__ w1, const float* __restrict__ w2,
    const float* __restrict__ w3, const float* __restrict__ w4,
    const float* __restrict__ w_in, const float* __restrict__ w_out,
    unsigned* __restrict__ pk) {
  const int bid = blockIdx.x;
  const int t = threadIdx.x;
  if (bid >= 256) {
    int idx = (bid - 256) * 256 + t;  // 0..32767
    {
      int kc = idx >> 12;
      int nt = (idx >> 8) & 15;
      int lane = (idx >> 2) & 63;
      int d = idx & 3;
      int n = nt * 16 + (lane & 15);
      int kb = kc * 32 + (lane >> 4) * 8 + d * 2;
      pk[idx] = rn_pair16(w_in[kb * 256 + n], w_in[(kb + 1) * 256 + n]);
    }
    int idx2 = idx + 32768;
    if (idx2 < 34816) {
      int r2 = idx2 - 32768;  // 0..2047
      int kc = r2 >> 8;
      int lane = (r2 >> 2) & 63;
      int d = r2 & 3;
      int n = lane & 15;
      int kb = kc * 32 + (lane >> 4) * 8 + d * 2;
      float v0 = (n < 10) ? w_out[kb * 10 + n] : 0.0f;
      float v1 = (n < 10) ? w_out[(kb + 1) * 10 + n] : 0.0f;
      pk[5 * 32768 + r2] = rn_pair16(v0, v1);
    }
    return;
  }
  const int m = bid >> 6;           // matrix 0..3
  const int r0 = (bid & 63) * 4;    // slab start row (4 rows)
  const float* __restrict__ W = (m == 0) ? w1 : (m == 1) ? w2 : (m == 2) ? w3 : w4;
  __shared__ float S[4][256];

  // init: P = 6I - W (slab rows r0..r0+3)
#pragma unroll
  for (int i = 0; i < 4; ++i) {
    int e = i * 256 + t;
    int r = e >> 8, c = e & 255;
    S[r][c] = (((r0 + r) == c) ? 6.0f : 0.0f) - W[(r0 + r) * 256 + c];
  }
  __syncthreads();

  const float coef[4] = {-15.0f, 20.0f, -15.0f, 6.0f};
#pragma unroll
  for (int step = 0; step < 4; ++step) {
    float acc[4];
#pragma unroll
    for (int r = 0; r < 4; ++r) acc[r] = 0.0f;
    for (int k = 0; k < 256; k += 4) {
      float4 sv[4];
#pragma unroll
      for (int r = 0; r < 4; ++r) sv[r] = *(const float4*)&S[r][k];
      float wv0 = W[(k + 0) * 256 + t];
      float wv1 = W[(k + 1) * 256 + t];
      float wv2 = W[(k + 2) * 256 + t];
      float wv3 = W[(k + 3) * 256 + t];
#pragma unroll
      for (int r = 0; r < 4; ++r) {
        acc[r] = fmaf(sv[r].x, wv0, acc[r]);
        acc[r] = fmaf(sv[r].y, wv1, acc[r]);
        acc[r] = fmaf(sv[r].z, wv2, acc[r]);
        acc[r] = fmaf(sv[r].w, wv3, acc[r]);
      }
    }
    __syncthreads();
    float cdiag = coef[step];
#pragma unroll
    for (int r = 0; r < 4; ++r)
      S[r][t] = acc[r] + (((r0 + r) == t) ? cdiag : 0.0f);
    __syncthreads();
  }

  // ---- pack slab: kc = r0>>5, quad = (r0>>3)&3, d in {d0, d0+1}, d0 = (r0&7)>>1 ----
  const int kc = r0 >> 5;
  const int quad = (r0 >> 3) & 3;
  const int d0 = (r0 & 7) >> 1;
#pragma unroll
  for (int i = 0; i < 2; ++i) {
    int q = i * 256 + t;        // 0..511 = nt*32 + n16*2 + dd
    int nt = q >> 5;            // 0..15
    int n16 = (q >> 1) & 15;
    int dd = q & 1;
    int n = nt * 16 + n16;
    int lane = quad * 16 + n16;
    unsigned word = rn_pair16(S[2 * dd][n], S[2 * dd + 1][n]);
    pk[(m + 1) * 32768 + kc * 4096 + nt * 256 + lane * 4 + (d0 + dd)] = word;
  }
}

// ---------------- Phase 2: fused3_k (K-split weight residency) ----------------
// Load this wave's 64-col weight slice for kc in [KB, KB+4) into wreg (64 VGPRs).
#define LOAD_W(LAYER, KB)                                                      \
  {                                                                            \
    const unsigned* pkl = pk + (LAYER) * 32768 + (KB) * 4096 + wv * 1024 + ln * 4; \
    _Pragma("unroll") for (int j = 0; j < 4; ++j)                              \
      _Pragma("unroll") for (int k4 = 0; k4 < 4; ++k4)                         \
        wreg[j][k4] = *(const short8*)(pkl + k4 * 4096 + j * 256);             \
  }

// One MFMA pass: tile U, kc in [KB, KB+4). 16 ds_read_b128 + 64 MFMA, no inner
// fences (compiler pipelines within the 128-arch budget); setprio(1) for the pass.
#define M_PASS(U, KB)                                                          \
  {                                                                            \
    const unsigned short* pl = zpl + (U) * 16384;                              \
    __builtin_amdgcn_s_setprio(1);                                             \
    _Pragma("unroll") for (int k4 = 0; k4 < 4; ++k4) {                         \
      short8 zf[4];                                                            \
      _Pragma("unroll") for (int mt = 0; mt < 4; ++mt) {                       \
        int mm = mt * 16 + n16;                                                \
        zf[mt] = *(const short8*)&pl[mm * 256 + (((((KB) + k4) * 4 + quad) ^ (mm & 31)) * 8)]; \
      }                                                                        \
      _Pragma("unroll") for (int mt = 0; mt < 4; ++mt)                         \
        _Pragma("unroll") for (int nt = 0; nt < 4; ++nt)                       \
          acc[U][mt][nt] = __builtin_amdgcn_mfma_f32_16x16x32_f16(             \
              wreg[nt][k4], zf[mt], acc[U][mt][nt], 0, 0, 0);                  \
    }                                                                          \
    __builtin_amdgcn_s_setprio(0);                                             \
    __builtin_amdgcn_sched_barrier(0);                                         \
  }

// Epilogue for tile U: bias/tanh, cvt_pkrtz pack into plane U.
#define E_TILE(U, BN, BI, DOTANH)                                              \
  {                                                                            \
    unsigned short* pl = zpl + (U) * 16384;                                    \
    _Pragma("unroll") for (int nt = 0; nt < 4; ++nt) {                         \
      int colb = wv * 64 + nt * 16 + quad * 4;                                 \
      float4 bi4 = make_float4(0.f, 0.f, 0.f, 0.f);                            \
      float4 bn4 = make_float4(0.f, 0.f, 0.f, 0.f);                            \
      if ((BI) != nullptr) bi4 = *(const float4*)((BI) + colb);                \
      if (DOTANH) bn4 = *(const float4*)((BN) + colb);                         \
      _Pragma("unroll") for (int mt = 0; mt < 4; ++mt) {                       \
        int row = mt * 16 + n16;                                               \
        float v0 = acc[U][mt][nt][0] + bi4.x;                                  \
        float v1 = acc[U][mt][nt][1] + bi4.y;                                  \
        float v2 = acc[U][mt][nt][2] + bi4.z;                                  \
        float v3 = acc[U][mt][nt][3] + bi4.w;                                  \
        if (DOTANH) {                                                          \
          v0 = v0 + tanh_fast(v0) + bn4.x;                                     \
          v1 = v1 + tanh_fast(v1) + bn4.y;                                     \
          v2 = v2 + tanh_fast(v2) + bn4.z;                                     \
          v3 = v3 + tanh_fast(v3) + bn4.w;                                     \
        }                                                                      \
        int idx = row * 256 + (((colb >> 3) ^ (row & 31)) * 8) + (colb & 7);   \
        uint2 zp;                                                              \
        zp.x = rtz_pair16(v0, v1);                                             \
        zp.y = rtz_pair16(v2, v3);                                             \
        *(uint2*)&pl[idx] = zp;                                                \
      }                                                                        \
    }                                                                          \
  }

__global__ __launch_bounds__(256)
__attribute__((amdgpu_waves_per_eu(2, 2)))  // 512-reg/SIMD file -> 128 arch + 128 AGPR per wave
void fused3_k(
    const float* __restrict__ x, const unsigned* __restrict__ pk,
    const float* __restrict__ b_in,
    const float* __restrict__ b1, const float* __restrict__ b2,
    const float* __restrict__ b3, const float* __restrict__ b4,
    const float* __restrict__ b_out, float* __restrict__ out) {
  __shared__ unsigned short zpl[2 * 64 * 256];  // two z-planes, 64 KB -> 2 blocks/CU
  const int t = threadIdx.x;
  const int ln = t & 63;
  const int wv = t >> 6;        // wave 0..3, owns cols [wv*64, wv*64+64)
  const int quad = ln >> 4;
  const int n16 = ln & 15;
  const int grow0 = blockIdx.x * 128;  // 128 rows/block (two 64-row tiles)

  short8 wreg[4][4];   // [nt][k4] — current kc-half weight slice, 64 VGPRs
  f32x4 acc[2][4][4];  // [tile][mt][nt] — 128 AGPRs (exactly the AGPR file)

  LOAD_W(0, 0);  // layer-0 kc0-3 in flight during x staging

  // ---- stage x as fp16 into both planes ----
#pragma unroll
  for (int i = 0; i < 32; ++i) {
    int e = i * 1024 + t * 4;
    int r = e >> 8, c = e & 255;     // r 0..127
    float4 v = *(const float4*)(x + (grow0 + r) * 256 + c);
    int u = r >> 6, rl = r & 63;
    int idx = u * 16384 + rl * 256 + (((c >> 3) ^ (rl & 31)) * 8) + (c & 7);
    uint2 zp;
    zp.x = rtz_pair16(v.x, v.y);
    zp.y = rtz_pair16(v.z, v.w);
    *(uint2*)&zpl[idx] = zp;
  }
  __syncthreads();

  const float* bnv[4] = {b1, b2, b3, b4};

  for (int layer = 0; layer < 5; ++layer) {
    const float* bn = (layer < 4) ? bnv[layer] : nullptr;
    const float* bi0 = (layer == 0) ? b_in : nullptr;
    const bool dt = (layer < 4);

#pragma unroll
    for (int u = 0; u < 2; ++u)
#pragma unroll
      for (int mt = 0; mt < 4; ++mt)
#pragma unroll
        for (int nt = 0; nt < 4; ++nt) acc[u][mt][nt] = (f32x4){0.f, 0.f, 0.f, 0.f};

    M_PASS(0, 0);            // tile 0, kc 0-3 (waits on wreg vmcnt)
    M_PASS(1, 0);            // tile 1, kc 0-3 (wreg resident)
    LOAD_W(layer, 4);        // wreg dead -> reload kc 4-7 (one exposed gap/layer)
    M_PASS(0, 4);            // tile 0, kc 4-7 -> same acc
    M_PASS(1, 4);            // tile 1, kc 4-7
    if (layer < 4) LOAD_W(layer + 1, 0);  // next layer kc0-3; hides under EPI+barrier
    __syncthreads();         // all plane reads done
    E_TILE(0, bn, bi0, dt);  // write plane 0
    E_TILE(1, bn, bi0, dt);  // write plane 1
    __syncthreads();         // planes ready for next layer
  }

  // ---- logits: wave wv reduces k-slice [wv*64, wv*64+64), both tiles ----
  {
    f32x4 lacc[2][4];
#pragma unroll
    for (int u = 0; u < 2; ++u)
#pragma unroll
      for (int mt = 0; mt < 4; ++mt) lacc[u][mt] = (f32x4){0.f, 0.f, 0.f, 0.f};
    const unsigned* pw = pk + 5 * 32768 + ln * 4;
#pragma unroll
    for (int kk = 0; kk < 2; ++kk) {
      int kc = wv * 2 + kk;
      short8 wh = *(const short8*)(pw + kc * 256);
#pragma unroll
      for (int u = 0; u < 2; ++u) {
        const unsigned short* pl = zpl + u * 16384;
#pragma unroll
        for (int mt = 0; mt < 4; ++mt) {
          int mm = mt * 16 + n16;
          short8 zf = *(const short8*)&pl[mm * 256 + (((kc * 4 + quad) ^ (mm & 31)) * 8)];
          lacc[u][mt] = __builtin_amdgcn_mfma_f32_16x16x32_f16(wh, zf, lacc[u][mt], 0, 0, 0);
        }
      }
    }
    __syncthreads();  // all z reads done before pbuf overwrites planes
    // pbuf_u overlays plane u: [wave][64 rows][16 cols] floats = 16 KB per tile
#pragma unroll
    for (int u = 0; u < 2; ++u) {
      float* pbuf = (float*)(zpl + u * 16384);
#pragma unroll
      for (int mt = 0; mt < 4; ++mt) {
        int addr = wv * 1024 + (mt * 16 + n16) * 16 + quad * 4;
        *(f32x4*)&pbuf[addr] = lacc[u][mt];
      }
    }
    __syncthreads();
    if (t < 128) {
      int u = t >> 6;
      int rl = t & 63;
      const float* pbuf = (const float*)(zpl + u * 16384);
      float lg[10];
      float mx = -1e30f;
#pragma unroll
      for (int j = 0; j < 10; ++j) {
        float s = b_out[j];
#pragma unroll
        for (int w2 = 0; w2 < 4; ++w2) s += pbuf[w2 * 1024 + rl * 16 + j];
        lg[j] = s;
        mx = fmaxf(mx, s);
      }
      float sum = 0.f;
#pragma unroll
      for (int j = 0; j < 10; ++j) {
        lg[j] = __expf(lg[j] - mx);
        sum += lg[j];
      }
      float inv = 1.0f / sum;
      float* op = out + (grow0 + t) * 10;
#pragma unroll
      for (int j = 0; j < 10; ++j) op[j] = lg[j] * inv;
    }
  }
}

extern "C" void kernel_launch(void* const* d_in, const int* in_sizes, int n_in,
                              void* d_out, int out_size, void* d_ws, size_t ws_size,
                              hipStream_t stream) {
  const float* x     = (const float*)d_in[0];
  const float* w_in  = (const float*)d_in[1];
  const float* b_in  = (const float*)d_in[2];
  const float* w_out = (const float*)d_in[3];
  const float* b_out = (const float*)d_in[4];
  const float* w1 = (const float*)d_in[5];
  const float* b1 = (const float*)d_in[6];
  const float* w2 = (const float*)d_in[7];
  const float* b2 = (const float*)d_in[8];
  const float* w3 = (const float*)d_in[9];
  const float* b3 = (const float*)d_in[10];
  const float* w4 = (const float*)d_in[11];
  const float* b4 = (const float*)d_in[12];
  float* out = (float*)d_out;

  unsigned* pk = (unsigned*)d_ws;  // 165888 dwords

  ns_poly_k<<<384, 256, 0, stream>>>(w1, w2, w3, w4, w_in, w_out, pk);
  fused3_k<<<512, 256, 0, stream>>>(x, pk, b_in, b1, b2, b3, b4, b_out, out);
}